// Round 8
// baseline (444.955 us; speedup 1.0000x reference)
//
#include <hip/hip_runtime.h>

// AdjacencyGenerator — round 8: DIAGNOSTIC ABLATION.
// Real pipeline (k_TW, k_Ac, k_node, k_edge_alpha, k_edge_out) is byte-
// identical to round 7 (PASS, absmax 0.0098, k_node ~92us as comparator).
// Appended: five stripped k_node variants on the same 782x256 grid, each
// isolating one phase, keep-alive via asm volatile (no DCE), writing only
// to scratch. Decision rule in journal: whichever variant retains the ~90us
// names the bottleneck; if all are fast, the slowness is emergent pressure.

typedef __attribute__((ext_vector_type(8))) short bf16x8;
typedef __attribute__((ext_vector_type(4))) float f32x4;

#define KEEP(v) asm volatile("" ::"v"(v))

__device__ __forceinline__ unsigned short f2bf(float f) {  // RNE
  unsigned int u = __float_as_uint(f);
  unsigned int r = (u + 0x7fffu + ((u >> 16) & 1u)) >> 16;
  return (unsigned short)r;
}
__device__ __forceinline__ float blo(unsigned int u) {
  return __uint_as_float(u << 16);
}
__device__ __forceinline__ float bhi(unsigned int u) {
  return __uint_as_float(u & 0xffff0000u);
}

// ==== setup kernel 1: T = W2@W1 | Wq/Wk/Wv -> bf16 (384 blks) | zero sArr ===
__global__ __launch_bounds__(128) void k_TW(
    const float* __restrict__ W2, const float* __restrict__ W1,
    const float* __restrict__ Wq, const float* __restrict__ Wk,
    const float* __restrict__ Wv, float* __restrict__ T,
    unsigned short* __restrict__ Wqb, unsigned short* __restrict__ Wkb,
    unsigned short* __restrict__ Wvb, float* __restrict__ sArr, int N) {
  const int b = blockIdx.x, t = threadIdx.x;
  if (b < 256) {
    float acc = 0.f;
    for (int k = 0; k < 512; ++k) acc += W2[b * 512 + k] * W1[k * 128 + t];
    T[b * 128 + t] = acc;
  } else if (b < 640) {
    const int idx = (b - 256) * 128 + t;
    const int m = idx >> 14, i = idx & 16383;
    const float* s = (m == 0) ? Wq : (m == 1) ? Wk : Wv;
    unsigned short* d = (m == 0) ? Wqb : (m == 1) ? Wkb : Wvb;
    d[i] = f2bf(s[i]);
  } else {
    const int i = (b - 640) * 128 + t;
    if (i < N) sArr[i] = 0.f;
  }
}

// ============ setup kernel 2: A3b = bf16(W3@T) | cfull | consts ============
__global__ __launch_bounds__(256) void k_Ac(
    const float* __restrict__ W3, const float* __restrict__ T,
    const float* __restrict__ W2, const float* __restrict__ b1,
    const float* __restrict__ b2, const float* __restrict__ b3,
    const float* __restrict__ g, const float* __restrict__ lb,
    const float* __restrict__ fg, const float* __restrict__ fb,
    const float* __restrict__ wv, unsigned short* __restrict__ A3b,
    float* __restrict__ cfull, float* __restrict__ C) {
  __shared__ float t1[256];
  __shared__ float cf[128];
  const int b = blockIdx.x, t = threadIdx.x;
  if (b < 64) {
    const int i = 2 * b + (t >> 7), j = t & 127;
    float acc = 0.f;
    for (int k = 0; k < 256; ++k) acc += W3[i * 256 + k] * T[k * 128 + j];
    A3b[i * 128 + j] = f2bf(acc);
    return;
  }
  float acc = b2[t];
  for (int c = 0; c < 512; ++c) acc += W2[t * 512 + c] * b1[c];
  t1[t] = acc;
  __syncthreads();
  if (t < 128) {
    float a = b3[t];
    for (int k = 0; k < 256; ++k) a += W3[t * 256 + k] * t1[k];
    cfull[t] = a;
    cf[t] = a;
  }
  __syncthreads();
  if (t < 64) {
    const int l = t;
    const float2 gv = ((const float2*)g)[l];
    const float2 bv = ((const float2*)lb)[l];
    const float2 fgv = ((const float2*)fg)[l];
    const float2 fbv = ((const float2*)fb)[l];
    const float2 wvv = ((const float2*)wv)[l];
    const float P0 = cf[2 * l] + bv.x, P1 = cf[2 * l + 1] + bv.y;
    const float w0 = fgv.x * wvv.x, w1 = fgv.y * wvv.y;
    float s[9];
    s[0] = P0 + P1;
    s[1] = P0 * w0 + P1 * w1;
    s[2] = P0 * P0 + P1 * P1;
    s[3] = gv.x + gv.y;
    s[4] = gv.x * w0 + gv.y * w1;
    s[5] = gv.x * gv.x + gv.y * gv.y;
    s[6] = P0 * gv.x + P1 * gv.y;
    s[7] = w0 + w1;
    s[8] = fbv.x * wvv.x + fbv.y * wvv.y;
#pragma unroll
    for (int m = 32; m >= 1; m >>= 1)
#pragma unroll
      for (int i = 0; i < 9; ++i) s[i] += __shfl_xor(s[i], m, 64);
    if (l == 0)
#pragma unroll
      for (int i = 0; i < 9; ++i) C[i] = s[i];
  }
}

// ============ real fused node kernel (r7 verbatim) ============
__global__ __launch_bounds__(256, 3) void k_node(
    const float* __restrict__ x, const unsigned short* __restrict__ Wqb,
    const unsigned short* __restrict__ Wkb,
    const unsigned short* __restrict__ Wvb,
    const unsigned short* __restrict__ A3b, const float* __restrict__ bq,
    const float* __restrict__ bk, const float* __restrict__ bv,
    const float* __restrict__ cfull, const float* __restrict__ g,
    const float* __restrict__ lb, const float* __restrict__ fg,
    const float* __restrict__ wvp, unsigned short* __restrict__ Qb,
    unsigned short* __restrict__ Kb, float* __restrict__ S, int N) {
  __shared__ unsigned short tile[64][136];
  const int t = threadIdx.x;
  const int nb = blockIdx.x * 64;
  for (int i = t; i < 64 * 32; i += 256) {
    const int j = i >> 5, c4 = i & 31;
    const int n = nb + j;
    float4 v = make_float4(0.f, 0.f, 0.f, 0.f);
    if (n < N) v = ((const float4*)x)[(size_t)n * 32 + c4];
    unsigned int lo = f2bf(v.x) | ((unsigned int)f2bf(v.y) << 16);
    unsigned int hi = f2bf(v.z) | ((unsigned int)f2bf(v.w) << 16);
    *(uint2*)&tile[j][c4 << 2] = make_uint2(lo, hi);
  }
  __syncthreads();
  const int wv16 = __builtin_amdgcn_readfirstlane(t >> 6) * 16;
  const int l = t & 63;
  const int ln = l & 15, g4 = l >> 4;
  bf16x8 af[4];
#pragma unroll
  for (int kb = 0; kb < 4; ++kb)
    af[kb] = *(const bf16x8*)&tile[wv16 + ln][kb * 32 + g4 * 8];

#pragma unroll
  for (int cb = 0; cb < 8; ++cb) {
    f32x4 acc = {0.f, 0.f, 0.f, 0.f};
#pragma unroll
    for (int kb = 0; kb < 4; ++kb) {
      const bf16x8 bfr =
          *(const bf16x8*)(Wqb + ((cb * 16 + ln) << 7) + kb * 32 + g4 * 8);
      acc = __builtin_amdgcn_mfma_f32_16x16x32_bf16(af[kb], bfr, acc, 0, 0, 0);
    }
    const int col = cb * 16 + ln;
    const float bs = bq[col];
#pragma unroll
    for (int r = 0; r < 4; ++r) tile[wv16 + g4 * 4 + r][col] = f2bf(acc[r] + bs);
  }
#pragma unroll
  for (int c = 0; c < 4; ++c) {
    const int row = wv16 + c * 4 + g4;
    const int n = nb + row;
    if (n < N)
      ((uint4*)(Qb + (size_t)n * 128))[ln] = *(const uint4*)&tile[row][ln * 8];
  }

#pragma unroll
  for (int cb = 0; cb < 8; ++cb) {
    f32x4 acc = {0.f, 0.f, 0.f, 0.f};
#pragma unroll
    for (int kb = 0; kb < 4; ++kb) {
      const bf16x8 bfr =
          *(const bf16x8*)(Wkb + ((cb * 16 + ln) << 7) + kb * 32 + g4 * 8);
      acc = __builtin_amdgcn_mfma_f32_16x16x32_bf16(af[kb], bfr, acc, 0, 0, 0);
    }
    const int col = cb * 16 + ln;
    const float bs = bk[col];
#pragma unroll
    for (int r = 0; r < 4; ++r) tile[wv16 + g4 * 4 + r][col] = f2bf(acc[r] + bs);
  }
#pragma unroll
  for (int c = 0; c < 4; ++c) {
    const int row = wv16 + c * 4 + g4;
    const int n = nb + row;
    if (n < N)
      ((uint4*)(Kb + (size_t)n * 128))[ln] = *(const uint4*)&tile[row][ln * 8];
  }

  float uf[8][4];
#pragma unroll
  for (int cb = 0; cb < 8; ++cb) {
    f32x4 acc = {0.f, 0.f, 0.f, 0.f};
#pragma unroll
    for (int kb = 0; kb < 4; ++kb) {
      const bf16x8 bfr =
          *(const bf16x8*)(Wvb + ((cb * 16 + ln) << 7) + kb * 32 + g4 * 8);
      acc = __builtin_amdgcn_mfma_f32_16x16x32_bf16(af[kb], bfr, acc, 0, 0, 0);
    }
    const int col = cb * 16 + ln;
    const float bs = bv[col];
#pragma unroll
    for (int r = 0; r < 4; ++r) {
      const float v = fmaxf(acc[r] + bs, 0.f);
      uf[cb][r] = v;
      tile[wv16 + g4 * 4 + r][col] = f2bf(v);
    }
  }

  bf16x8 af2[4];
#pragma unroll
  for (int kb = 0; kb < 4; ++kb)
    af2[kb] = *(const bf16x8*)&tile[wv16 + ln][kb * 32 + g4 * 8];
  float vmf[8][4];
#pragma unroll
  for (int cb = 0; cb < 8; ++cb) {
    f32x4 acc = {0.f, 0.f, 0.f, 0.f};
#pragma unroll
    for (int kb = 0; kb < 4; ++kb) {
      const bf16x8 bfr =
          *(const bf16x8*)(A3b + ((cb * 16 + ln) << 7) + kb * 32 + g4 * 8);
      acc = __builtin_amdgcn_mfma_f32_16x16x32_bf16(af2[kb], bfr, acc, 0, 0, 0);
    }
#pragma unroll
    for (int r = 0; r < 4; ++r) vmf[cb][r] = acc[r];
  }

  float gc[8], wc[8], Pc[8];
#pragma unroll
  for (int cb = 0; cb < 8; ++cb) {
    const int col = cb * 16 + ln;
    gc[cb] = g[col];
    wc[cb] = fg[col] * wvp[col];
    Pc[cb] = cfull[col] + lb[col];
  }

#pragma unroll
  for (int r = 0; r < 4; ++r) {
    const int row = wv16 + g4 * 4 + r;
    const int nrow = (nb + row < N) ? (nb + row) : (N - 1);
    float s[23];
#pragma unroll
    for (int i = 0; i < 23; ++i) s[i] = 0.f;
#pragma unroll
    for (int cb = 0; cb < 8; ++cb) {
      const float xv = x[(size_t)nrow * 128 + cb * 16 + ln];
      const float u = uf[cb][r];
      const float v = vmf[cb][r];
      const float gg = gc[cb], ww = wc[cb], PP = Pc[cb];
      const float xg = xv * gg, ug = u * gg;
      s[0] += xv;
      s[1] += u;
      s[2] += xv * xv;
      s[3] += xv * u;
      s[4] += u * u;
      s[5] += v;
      s[6] += v * ww;
      s[7] += xg;
      s[8] += ug;
      s[9] += xg * ww;
      s[10] += ug * ww;
      s[11] += PP * v;
      s[12] += v * v;
      s[13] += PP * xg;
      s[14] += PP * ug;
      s[15] += v * xg;
      s[16] += v * ug;
      s[17] += v * gg;
      s[18] += xg * xg;
      s[19] += xg * ug;
      s[20] += ug * ug;
      s[21] += xg * gg;
      s[22] += ug * gg;
    }
#pragma unroll
    for (int m = 1; m <= 8; m <<= 1)
#pragma unroll
      for (int i = 0; i < 23; ++i) s[i] += __shfl_xor(s[i], m, 64);
    const int n2 = nb + row;
    if (ln == 0 && n2 < N) {
      float* o = S + (size_t)n2 * 24;
      o[0] = s[0] * (1.f / 128.f);
      o[1] = s[1] * (1.f / 128.f);
#pragma unroll
      for (int i = 2; i < 23; ++i) o[i] = s[i];
      o[23] = 0.f;
    }
  }
}

// ============ edge pass 1 (unchanged) ============
__global__ __launch_bounds__(256) void k_edge_alpha(
    const int* __restrict__ ei, const unsigned short* __restrict__ Qb,
    const unsigned short* __restrict__ Kb, float* __restrict__ eArr,
    float* __restrict__ sArr, int E) {
  const int t = threadIdx.x;
  const int l = t & 15;
  const int e = blockIdx.x * 16 + (t >> 4);
  if (e >= E) return;
  const int src = ei[e];
  const int dst = ei[E + e];
  const uint4 qv = ((const uint4*)Qb)[(size_t)src * 16 + l];
  const uint4 kv = ((const uint4*)Kb)[(size_t)dst * 16 + l];
  float p = blo(qv.x) * blo(kv.x);
  p = fmaf(bhi(qv.x), bhi(kv.x), p);
  p = fmaf(blo(qv.y), blo(kv.y), p);
  p = fmaf(bhi(qv.y), bhi(kv.y), p);
  p = fmaf(blo(qv.z), blo(kv.z), p);
  p = fmaf(bhi(qv.z), bhi(kv.z), p);
  p = fmaf(blo(qv.w), blo(kv.w), p);
  p = fmaf(bhi(qv.w), bhi(kv.w), p);
#pragma unroll
  for (int m = 8; m >= 1; m >>= 1) p += __shfl_xor(p, m, 16);
  if (l == 0) {
    const float ex = __expf(p);
    eArr[e] = ex;
    atomicAdd(&sArr[dst], ex);
  }
}

// ============ edge pass 2 (unchanged) ============
__global__ __launch_bounds__(256) void k_edge_out(
    const int* __restrict__ ei, const float* __restrict__ eArr,
    const float* __restrict__ sArr, const float* __restrict__ S,
    const float* __restrict__ C, const float* __restrict__ bvec,
    float* __restrict__ out, int E) {
  const int e = blockIdx.x * 256 + threadIdx.x;
  if (e >= E) return;
  const int dst = ei[E + e];
  const float t = eArr[e] / (sArr[dst] + 1e-16f);
  const float4* o = (const float4*)(S + (size_t)dst * 24);
  const float4 q0 = o[0], q1 = o[1], q2 = o[2], q3 = o[3], q4 = o[4],
               q5 = o[5];
  const float mx = q0.x, mU = q0.y, sxx = q0.z, sxu = q0.w;
  const float suu = q1.x, sv = q1.y, svw = q1.z, sxg = q1.w;
  const float sug = q2.x, sxgw = q2.y, sugw = q2.z, spv = q2.w;
  const float svv = q3.x, pxg = q3.y, pug = q3.z, vxg = q3.w;
  const float vug = q4.x, vg = q4.y, xgxg = q4.z, xgug = q4.w;
  const float ugug = q5.x, xgg = q5.y, ugg = q5.z;
  const float SP = C[0], SPw = C[1], SPP = C[2], SG = C[3], SGw = C[4],
              GG = C[5], SPG = C[6], Sw = C[7], s0 = C[8];
  const float mu = mx + t * mU;
  const float qy = (sxx + 2.f * t * sxu + t * t * suu) * (1.f / 128.f);
  const float i1 = rsqrtf(qy - mu * mu + 1e-5f);
  const float sz = SP + t * sv + i1 * (sxg + t * sug - mu * SG);
  const float szw = SPw + t * svw + i1 * (sxgw + t * sugw - mu * SGw);
  const float cross = pxg + t * (pug + vxg) + t * t * vug - mu * (SPG + t * vg);
  const float rr = xgxg + 2.f * t * xgug + t * t * ugug -
                   2.f * mu * (xgg + t * ugg) + mu * mu * GG;
  const float szz =
      SPP + 2.f * t * spv + t * t * svv + 2.f * i1 * cross + i1 * i1 * rr;
  const float muz = sz * (1.f / 128.f);
  const float varz = szz * (1.f / 128.f) - muz * muz;
  const float iz = rsqrtf(varz + 1e-5f);
  out[e] = iz * (szw - muz * Sw) + s0 + bvec[0];
}

// ===================== DIAGNOSTICS (write only to scratch) =====================

// D1: the per-wave weight-fragment global loads, nothing else.
__global__ __launch_bounds__(256, 3) void d_wload(
    const unsigned short* __restrict__ Wqb,
    const unsigned short* __restrict__ Wkb,
    const unsigned short* __restrict__ Wvb,
    const unsigned short* __restrict__ A3b) {
  const int l = threadIdx.x & 63;
  const int ln = l & 15, g4 = l >> 4;
  uint4 acc = {0u, 0u, 0u, 0u};
  const unsigned short* mats[4] = {Wqb, Wkb, Wvb, A3b};
#pragma unroll
  for (int m = 0; m < 4; ++m) {
#pragma unroll
    for (int cb = 0; cb < 8; ++cb)
#pragma unroll
      for (int kb = 0; kb < 4; ++kb) {
        const uint4 v =
            *(const uint4*)(mats[m] + ((cb * 16 + ln) << 7) + kb * 32 + g4 * 8);
        acc.x += v.x;
        acc.y += v.y;
        acc.z += v.z;
        acc.w += v.w;
      }
  }
  KEEP(acc.x);
  KEEP(acc.y);
  KEEP(acc.z);
  KEEP(acc.w);
}

// D2: staging + the 4 MFMA passes; no global stores, no stats.
__global__ __launch_bounds__(256, 3) void d_mfma(
    const float* __restrict__ x, const unsigned short* __restrict__ Wqb,
    const unsigned short* __restrict__ Wkb,
    const unsigned short* __restrict__ Wvb,
    const unsigned short* __restrict__ A3b, const float* __restrict__ bq,
    const float* __restrict__ bk, const float* __restrict__ bv, int N) {
  __shared__ unsigned short tile[64][136];
  const int t = threadIdx.x;
  const int nb = blockIdx.x * 64;
  for (int i = t; i < 64 * 32; i += 256) {
    const int j = i >> 5, c4 = i & 31;
    const int n = nb + j;
    float4 v = make_float4(0.f, 0.f, 0.f, 0.f);
    if (n < N) v = ((const float4*)x)[(size_t)n * 32 + c4];
    unsigned int lo = f2bf(v.x) | ((unsigned int)f2bf(v.y) << 16);
    unsigned int hi = f2bf(v.z) | ((unsigned int)f2bf(v.w) << 16);
    *(uint2*)&tile[j][c4 << 2] = make_uint2(lo, hi);
  }
  __syncthreads();
  const int wv16 = __builtin_amdgcn_readfirstlane(t >> 6) * 16;
  const int l = t & 63;
  const int ln = l & 15, g4 = l >> 4;
  bf16x8 af[4];
#pragma unroll
  for (int kb = 0; kb < 4; ++kb)
    af[kb] = *(const bf16x8*)&tile[wv16 + ln][kb * 32 + g4 * 8];
  float live = 0.f;
#pragma unroll
  for (int cb = 0; cb < 8; ++cb) {  // Q
    f32x4 acc = {0.f, 0.f, 0.f, 0.f};
#pragma unroll
    for (int kb = 0; kb < 4; ++kb)
      acc = __builtin_amdgcn_mfma_f32_16x16x32_bf16(
          af[kb],
          *(const bf16x8*)(Wqb + ((cb * 16 + ln) << 7) + kb * 32 + g4 * 8), acc,
          0, 0, 0);
    const int col = cb * 16 + ln;
#pragma unroll
    for (int r = 0; r < 4; ++r) {
      const float v = acc[r] + bq[col];
      live += v;
      tile[wv16 + g4 * 4 + r][col] = f2bf(v);
    }
  }
#pragma unroll
  for (int cb = 0; cb < 8; ++cb) {  // K
    f32x4 acc = {0.f, 0.f, 0.f, 0.f};
#pragma unroll
    for (int kb = 0; kb < 4; ++kb)
      acc = __builtin_amdgcn_mfma_f32_16x16x32_bf16(
          af[kb],
          *(const bf16x8*)(Wkb + ((cb * 16 + ln) << 7) + kb * 32 + g4 * 8), acc,
          0, 0, 0);
    const int col = cb * 16 + ln;
#pragma unroll
    for (int r = 0; r < 4; ++r) {
      const float v = acc[r] + bk[col];
      live += v;
      tile[wv16 + g4 * 4 + r][col] = f2bf(v);
    }
  }
  float uf[8][4];
#pragma unroll
  for (int cb = 0; cb < 8; ++cb) {  // V
    f32x4 acc = {0.f, 0.f, 0.f, 0.f};
#pragma unroll
    for (int kb = 0; kb < 4; ++kb)
      acc = __builtin_amdgcn_mfma_f32_16x16x32_bf16(
          af[kb],
          *(const bf16x8*)(Wvb + ((cb * 16 + ln) << 7) + kb * 32 + g4 * 8), acc,
          0, 0, 0);
    const int col = cb * 16 + ln;
#pragma unroll
    for (int r = 0; r < 4; ++r) {
      const float v = fmaxf(acc[r] + bv[col], 0.f);
      uf[cb][r] = v;
      tile[wv16 + g4 * 4 + r][col] = f2bf(v);
    }
  }
  bf16x8 af2[4];
#pragma unroll
  for (int kb = 0; kb < 4; ++kb)
    af2[kb] = *(const bf16x8*)&tile[wv16 + ln][kb * 32 + g4 * 8];
#pragma unroll
  for (int cb = 0; cb < 8; ++cb) {  // VM
    f32x4 acc = {0.f, 0.f, 0.f, 0.f};
#pragma unroll
    for (int kb = 0; kb < 4; ++kb)
      acc = __builtin_amdgcn_mfma_f32_16x16x32_bf16(
          af2[kb],
          *(const bf16x8*)(A3b + ((cb * 16 + ln) << 7) + kb * 32 + g4 * 8), acc,
          0, 0, 0);
#pragma unroll
    for (int r = 0; r < 4; ++r) live += acc[r] + uf[cb][r];
  }
  KEEP(live);
}

// D3: D2 + the coalesced Qb/Kb stores (to scratch clones).
__global__ __launch_bounds__(256, 3) void d_fstore(
    const float* __restrict__ x, const unsigned short* __restrict__ Wqb,
    const unsigned short* __restrict__ Wkb,
    const unsigned short* __restrict__ Wvb,
    const unsigned short* __restrict__ A3b, const float* __restrict__ bq,
    const float* __restrict__ bk, const float* __restrict__ bv,
    unsigned short* __restrict__ dQ, unsigned short* __restrict__ dK, int N) {
  __shared__ unsigned short tile[64][136];
  const int t = threadIdx.x;
  const int nb = blockIdx.x * 64;
  for (int i = t; i < 64 * 32; i += 256) {
    const int j = i >> 5, c4 = i & 31;
    const int n = nb + j;
    float4 v = make_float4(0.f, 0.f, 0.f, 0.f);
    if (n < N) v = ((const float4*)x)[(size_t)n * 32 + c4];
    unsigned int lo = f2bf(v.x) | ((unsigned int)f2bf(v.y) << 16);
    unsigned int hi = f2bf(v.z) | ((unsigned int)f2bf(v.w) << 16);
    *(uint2*)&tile[j][c4 << 2] = make_uint2(lo, hi);
  }
  __syncthreads();
  const int wv16 = __builtin_amdgcn_readfirstlane(t >> 6) * 16;
  const int l = t & 63;
  const int ln = l & 15, g4 = l >> 4;
  bf16x8 af[4];
#pragma unroll
  for (int kb = 0; kb < 4; ++kb)
    af[kb] = *(const bf16x8*)&tile[wv16 + ln][kb * 32 + g4 * 8];
  float live = 0.f;
#pragma unroll
  for (int cb = 0; cb < 8; ++cb) {  // Q
    f32x4 acc = {0.f, 0.f, 0.f, 0.f};
#pragma unroll
    for (int kb = 0; kb < 4; ++kb)
      acc = __builtin_amdgcn_mfma_f32_16x16x32_bf16(
          af[kb],
          *(const bf16x8*)(Wqb + ((cb * 16 + ln) << 7) + kb * 32 + g4 * 8), acc,
          0, 0, 0);
    const int col = cb * 16 + ln;
#pragma unroll
    for (int r = 0; r < 4; ++r)
      tile[wv16 + g4 * 4 + r][col] = f2bf(acc[r] + bq[col]);
  }
#pragma unroll
  for (int c = 0; c < 4; ++c) {
    const int row = wv16 + c * 4 + g4;
    const int n = nb + row;
    if (n < N)
      ((uint4*)(dQ + (size_t)n * 128))[ln] = *(const uint4*)&tile[row][ln * 8];
  }
#pragma unroll
  for (int cb = 0; cb < 8; ++cb) {  // K
    f32x4 acc = {0.f, 0.f, 0.f, 0.f};
#pragma unroll
    for (int kb = 0; kb < 4; ++kb)
      acc = __builtin_amdgcn_mfma_f32_16x16x32_bf16(
          af[kb],
          *(const bf16x8*)(Wkb + ((cb * 16 + ln) << 7) + kb * 32 + g4 * 8), acc,
          0, 0, 0);
    const int col = cb * 16 + ln;
#pragma unroll
    for (int r = 0; r < 4; ++r)
      tile[wv16 + g4 * 4 + r][col] = f2bf(acc[r] + bk[col]);
  }
#pragma unroll
  for (int c = 0; c < 4; ++c) {
    const int row = wv16 + c * 4 + g4;
    const int n = nb + row;
    if (n < N)
      ((uint4*)(dK + (size_t)n * 128))[ln] = *(const uint4*)&tile[row][ln * 8];
  }
  float uf[8][4];
#pragma unroll
  for (int cb = 0; cb < 8; ++cb) {  // V
    f32x4 acc = {0.f, 0.f, 0.f, 0.f};
#pragma unroll
    for (int kb = 0; kb < 4; ++kb)
      acc = __builtin_amdgcn_mfma_f32_16x16x32_bf16(
          af[kb],
          *(const bf16x8*)(Wvb + ((cb * 16 + ln) << 7) + kb * 32 + g4 * 8), acc,
          0, 0, 0);
    const int col = cb * 16 + ln;
#pragma unroll
    for (int r = 0; r < 4; ++r) {
      const float v = fmaxf(acc[r] + bv[col], 0.f);
      uf[cb][r] = v;
      tile[wv16 + g4 * 4 + r][col] = f2bf(v);
    }
  }
  bf16x8 af2[4];
#pragma unroll
  for (int kb = 0; kb < 4; ++kb)
    af2[kb] = *(const bf16x8*)&tile[wv16 + ln][kb * 32 + g4 * 8];
#pragma unroll
  for (int cb = 0; cb < 8; ++cb) {  // VM
    f32x4 acc = {0.f, 0.f, 0.f, 0.f};
#pragma unroll
    for (int kb = 0; kb < 4; ++kb)
      acc = __builtin_amdgcn_mfma_f32_16x16x32_bf16(
          af2[kb],
          *(const bf16x8*)(A3b + ((cb * 16 + ln) << 7) + kb * 32 + g4 * 8), acc,
          0, 0, 0);
#pragma unroll
    for (int r = 0; r < 4; ++r) live += acc[r] + uf[cb][r];
  }
  KEEP(live);
}

// D4: MFMA passes with weights staged in LDS (XOR-swizzled, T2/G4 fix).
__global__ __launch_bounds__(256, 3) void d_ldsw(
    const float* __restrict__ x, const unsigned short* __restrict__ Wqb,
    const unsigned short* __restrict__ Wkb,
    const unsigned short* __restrict__ Wvb,
    const unsigned short* __restrict__ A3b, const float* __restrict__ bq,
    const float* __restrict__ bk, const float* __restrict__ bv, int N) {
  __shared__ unsigned short tile[64][136];
  __shared__ unsigned short wl[128 * 128];  // 32 KB, swizzled rows
  const int t = threadIdx.x;
  const int nb = blockIdx.x * 64;
  for (int i = t; i < 64 * 32; i += 256) {
    const int j = i >> 5, c4 = i & 31;
    const int n = nb + j;
    float4 v = make_float4(0.f, 0.f, 0.f, 0.f);
    if (n < N) v = ((const float4*)x)[(size_t)n * 32 + c4];
    unsigned int lo = f2bf(v.x) | ((unsigned int)f2bf(v.y) << 16);
    unsigned int hi = f2bf(v.z) | ((unsigned int)f2bf(v.w) << 16);
    *(uint2*)&tile[j][c4 << 2] = make_uint2(lo, hi);
  }
  __syncthreads();
  const int wv16 = __builtin_amdgcn_readfirstlane(t >> 6) * 16;
  const int l = t & 63;
  const int ln = l & 15, g4 = l >> 4;
  bf16x8 af[4];
#pragma unroll
  for (int kb = 0; kb < 4; ++kb)
    af[kb] = *(const bf16x8*)&tile[wv16 + ln][kb * 32 + g4 * 8];
  float live = 0.f;
  float uf[8][4];
  bf16x8 af2[4];
  const unsigned short* mats[4] = {Wqb, Wkb, Wvb, A3b};
  const float* bias[4] = {bq, bk, bv, nullptr};
#pragma unroll
  for (int m = 0; m < 4; ++m) {
    __syncthreads();  // prior pass done reading wl
#pragma unroll
    for (int c = 0; c < 8; ++c) {  // stage 32 KB swizzled, coalesced reads
      const int idx = c * 256 + t;
      const int byte = idx * 16;
      const int row = byte >> 8;
      const int swz = byte ^ ((row & 7) << 4);
      *(uint4*)((char*)wl + swz) = *(const uint4*)((const char*)mats[m] + byte);
    }
    __syncthreads();
#pragma unroll
    for (int cb = 0; cb < 8; ++cb) {
      f32x4 acc = {0.f, 0.f, 0.f, 0.f};
#pragma unroll
      for (int kb = 0; kb < 4; ++kb) {
        const int byteW = ((cb * 16 + ln) << 8) + kb * 64 + g4 * 16;
        const int swzW = byteW ^ ((ln & 7) << 4);
        const bf16x8 bfr = *(const bf16x8*)((const char*)wl + swzW);
        acc = __builtin_amdgcn_mfma_f32_16x16x32_bf16(
            (m == 3) ? af2[kb] : af[kb], bfr, acc, 0, 0, 0);
      }
      const int col = cb * 16 + ln;
#pragma unroll
      for (int r = 0; r < 4; ++r) {
        float v = acc[r] + ((m == 3) ? 0.f : bias[m][col]);
        if (m == 2) {
          v = fmaxf(v, 0.f);
          uf[cb][r] = v;
          tile[wv16 + g4 * 4 + r][col] = f2bf(v);
        } else if (m == 3) {
          live += v + uf[cb][r];
        } else {
          live += v;
          tile[wv16 + g4 * 4 + r][col] = f2bf(v);
        }
      }
    }
    if (m == 2) {
#pragma unroll
      for (int kb = 0; kb < 4; ++kb)
        af2[kb] = *(const bf16x8*)&tile[wv16 + ln][kb * 32 + g4 * 8];
    }
  }
  KEEP(live);
}

// D5: the stats phase alone (global x reads + 23 sums + shuffles + S store).
__global__ __launch_bounds__(256, 3) void d_stats(
    const float* __restrict__ x, const float* __restrict__ cfull,
    const float* __restrict__ g, const float* __restrict__ lb,
    const float* __restrict__ fg, const float* __restrict__ wvp,
    float* __restrict__ Sd, int N) {
  const int t = threadIdx.x;
  const int nb = blockIdx.x * 64;
  const int l = t & 63;
  const int ln = l & 15, g4 = l >> 4;
  const int wv16 = __builtin_amdgcn_readfirstlane(t >> 6) * 16;
  float uf[8][4], vmf[8][4];
#pragma unroll
  for (int cb = 0; cb < 8; ++cb)
#pragma unroll
    for (int r = 0; r < 4; ++r) {
      uf[cb][r] = (float)((cb * 4 + r + t) & 15) * 0.25f;
      vmf[cb][r] = uf[cb][r] * 0.5f - 1.f;
    }
  float gc[8], wc[8], Pc[8];
#pragma unroll
  for (int cb = 0; cb < 8; ++cb) {
    const int col = cb * 16 + ln;
    gc[cb] = g[col];
    wc[cb] = fg[col] * wvp[col];
    Pc[cb] = cfull[col] + lb[col];
  }
#pragma unroll
  for (int r = 0; r < 4; ++r) {
    const int row = wv16 + g4 * 4 + r;
    const int nrow = (nb + row < N) ? (nb + row) : (N - 1);
    float s[23];
#pragma unroll
    for (int i = 0; i < 23; ++i) s[i] = 0.f;
#pragma unroll
    for (int cb = 0; cb < 8; ++cb) {
      const float xv = x[(size_t)nrow * 128 + cb * 16 + ln];
      const float u = uf[cb][r];
      const float v = vmf[cb][r];
      const float gg = gc[cb], ww = wc[cb], PP = Pc[cb];
      const float xg = xv * gg, ug = u * gg;
      s[0] += xv;
      s[1] += u;
      s[2] += xv * xv;
      s[3] += xv * u;
      s[4] += u * u;
      s[5] += v;
      s[6] += v * ww;
      s[7] += xg;
      s[8] += ug;
      s[9] += xg * ww;
      s[10] += ug * ww;
      s[11] += PP * v;
      s[12] += v * v;
      s[13] += PP * xg;
      s[14] += PP * ug;
      s[15] += v * xg;
      s[16] += v * ug;
      s[17] += v * gg;
      s[18] += xg * xg;
      s[19] += xg * ug;
      s[20] += ug * ug;
      s[21] += xg * gg;
      s[22] += ug * gg;
    }
#pragma unroll
    for (int m = 1; m <= 8; m <<= 1)
#pragma unroll
      for (int i = 0; i < 23; ++i) s[i] += __shfl_xor(s[i], m, 64);
    const int n2 = nb + row;
    if (ln == 0 && n2 < N) {
      float* o = Sd + (size_t)n2 * 24;
      o[0] = s[0] * (1.f / 128.f);
      o[1] = s[1] * (1.f / 128.f);
#pragma unroll
      for (int i = 2; i < 23; ++i) o[i] = s[i];
      o[23] = 0.f;
    }
  }
}

extern "C" void kernel_launch(void* const* d_in, const int* in_sizes, int n_in,
                              void* d_out, int out_size, void* d_ws,
                              size_t ws_size, hipStream_t stream) {
  const int* ei = (const int*)d_in[0];
  const float* x = (const float*)d_in[1];
  const float* Wq = (const float*)d_in[2];
  const float* bq = (const float*)d_in[3];
  const float* Wk = (const float*)d_in[4];
  const float* bk = (const float*)d_in[5];
  const float* Wv = (const float*)d_in[6];
  const float* bv = (const float*)d_in[7];
  const float* ln_g = (const float*)d_in[8];
  const float* ln_b = (const float*)d_in[9];
  const float* W1 = (const float*)d_in[10];
  const float* b1 = (const float*)d_in[11];
  const float* W2 = (const float*)d_in[12];
  const float* b2 = (const float*)d_in[13];
  const float* W3 = (const float*)d_in[14];
  const float* b3 = (const float*)d_in[15];
  const float* Wvec = (const float*)d_in[16];
  const float* bvec = (const float*)d_in[17];
  const float* fn_g = (const float*)d_in[18];
  const float* fn_b = (const float*)d_in[19];

  const int E = in_sizes[0] / 2;
  const int N = in_sizes[1] / 128;

  const float* Wq2 = Wq + 2 * 128 * 128;
  const float* bq2 = bq + 2 * 128;
  const float* Wk2 = Wk + 2 * 128 * 128;
  const float* bk2 = bk + 2 * 128;
  const float* Wv2 = Wv + 2 * 128 * 128;
  const float* bv2 = bv + 2 * 128;
  const float* g2 = ln_g + 2 * 128;
  const float* lb2 = ln_b + 2 * 128;

  float* ws = (float*)d_ws;
  float* T = ws;
  float* cfull = T + 32768;
  float* consts = cfull + 128;
  unsigned short* Wqb = (unsigned short*)(consts + 16);
  unsigned short* Wkb = Wqb + 16384;
  unsigned short* Wvb = Wkb + 16384;
  unsigned short* A3b = Wvb + 16384;
  float* fbase = consts + 16 + 32768;
  unsigned short* Qb = (unsigned short*)fbase;
  unsigned short* Kb = Qb + (size_t)N * 128;
  float* S = fbase + (size_t)N * 128;
  float* eArr = S + (size_t)N * 24;
  float* sArr = eArr + E;
  // diagnostics scratch
  float* dump = sArr + N;
  unsigned short* dQ = (unsigned short*)dump;      // N*128 us
  unsigned short* dK = dQ + (size_t)N * 128;       // N*128 us
  float* dS = dump + (size_t)N * 128;              // N*24 floats

  const int zblk = (N + 127) / 128;
  k_TW<<<640 + zblk, 128, 0, stream>>>(W2, W1, Wq2, Wk2, Wv2, T, Wqb, Wkb,
                                       Wvb, sArr, N);
  k_Ac<<<65, 256, 0, stream>>>(W3, T, W2, b1, b2, b3, g2, lb2, fn_g, fn_b,
                               Wvec, A3b, cfull, consts);

  const int nblk = (N + 63) / 64;
  k_node<<<nblk, 256, 0, stream>>>(x, Wqb, Wkb, Wvb, A3b, bq2, bk2, bv2,
                                   cfull, g2, lb2, fn_g, Wvec, Qb, Kb, S, N);
  const int ablk = (E + 15) / 16;
  k_edge_alpha<<<ablk, 256, 0, stream>>>(ei, Qb, Kb, eArr, sArr, E);
  const int oblk = (E + 255) / 256;
  k_edge_out<<<oblk, 256, 0, stream>>>(ei, eArr, sArr, S, consts, bvec,
                                       (float*)d_out, E);

  // ---- diagnostics (after real pipeline; scratch-only) ----
  d_wload<<<nblk, 256, 0, stream>>>(Wqb, Wkb, Wvb, A3b);
  d_mfma<<<nblk, 256, 0, stream>>>(x, Wqb, Wkb, Wvb, A3b, bq2, bk2, bv2, N);
  d_fstore<<<nblk, 256, 0, stream>>>(x, Wqb, Wkb, Wvb, A3b, bq2, bk2, bv2, dQ,
                                     dK, N);
  d_ldsw<<<nblk, 256, 0, stream>>>(x, Wqb, Wkb, Wvb, A3b, bq2, bk2, bv2, N);
  d_stats<<<nblk, 256, 0, stream>>>(x, cfull, g2, lb2, fn_g, Wvec, dS, N);
}

// Round 10
// 181.351 us; speedup vs baseline: 2.4536x; 2.4536x over previous
//
#include <hip/hip_runtime.h>

// AdjacencyGenerator — round 10 (= round 9 + WFRAG precedence fix).
// Algebra: only layer 2 live; MLP affine -> A3 = W3@W2@W1 (+cfull);
// relu(alpha*v) = alpha*relu(v); both layernorms + final dot collapse to a
// closed form in the scalar t = alpha given 23 per-node sums S[dst].
// Theory (from r8 ablation): k_node's invariant ~90us is per-wave redundant
// weight traffic — every wave demand-loads all 128KB of weights from L2 as
// 16-segment scattered b128 reads. Fix: stage each matrix into a 32KB
// XOR-swizzled LDS buffer once per block; MFMAs read from LDS.
// r9 bug: `ptr + off ^ swz` parsed as `(ptr+off) ^ swz` (pointer^int). Now
// the XOR is applied to the integer offset before the pointer add.

typedef __attribute__((ext_vector_type(8))) short bf16x8;
typedef __attribute__((ext_vector_type(4))) float f32x4;

__device__ __forceinline__ unsigned short f2bf(float f) {  // RNE
  unsigned int u = __float_as_uint(f);
  unsigned int r = (u + 0x7fffu + ((u >> 16) & 1u)) >> 16;
  return (unsigned short)r;
}
__device__ __forceinline__ float blo(unsigned int u) {
  return __uint_as_float(u << 16);
}
__device__ __forceinline__ float bhi(unsigned int u) {
  return __uint_as_float(u & 0xffff0000u);
}

// ==== setup kernel 1: T = W2@W1 | Wq/Wk/Wv -> bf16 (384 blks) | zero sArr ===
__global__ __launch_bounds__(128) void k_TW(
    const float* __restrict__ W2, const float* __restrict__ W1,
    const float* __restrict__ Wq, const float* __restrict__ Wk,
    const float* __restrict__ Wv, float* __restrict__ T,
    unsigned short* __restrict__ Wqb, unsigned short* __restrict__ Wkb,
    unsigned short* __restrict__ Wvb, float* __restrict__ sArr, int N) {
  const int b = blockIdx.x, t = threadIdx.x;
  if (b < 256) {
    float acc = 0.f;
    for (int k = 0; k < 512; ++k) acc += W2[b * 512 + k] * W1[k * 128 + t];
    T[b * 128 + t] = acc;
  } else if (b < 640) {  // 384 blocks * 128 threads = 3 * 16384 elements
    const int idx = (b - 256) * 128 + t;
    const int m = idx >> 14, i = idx & 16383;
    const float* s = (m == 0) ? Wq : (m == 1) ? Wk : Wv;
    unsigned short* d = (m == 0) ? Wqb : (m == 1) ? Wkb : Wvb;
    d[i] = f2bf(s[i]);
  } else {
    const int i = (b - 640) * 128 + t;
    if (i < N) sArr[i] = 0.f;
  }
}

// ============ setup kernel 2: A3b = bf16(W3@T) | cfull | consts ============
__global__ __launch_bounds__(256) void k_Ac(
    const float* __restrict__ W3, const float* __restrict__ T,
    const float* __restrict__ W2, const float* __restrict__ b1,
    const float* __restrict__ b2, const float* __restrict__ b3,
    const float* __restrict__ g, const float* __restrict__ lb,
    const float* __restrict__ fg, const float* __restrict__ fb,
    const float* __restrict__ wv, unsigned short* __restrict__ A3b,
    float* __restrict__ cfull, float* __restrict__ C) {
  __shared__ float t1[256];
  __shared__ float cf[128];
  const int b = blockIdx.x, t = threadIdx.x;
  if (b < 64) {  // two rows of A3 per block
    const int i = 2 * b + (t >> 7), j = t & 127;
    float acc = 0.f;
    for (int k = 0; k < 256; ++k) acc += W3[i * 256 + k] * T[k * 128 + j];
    A3b[i * 128 + j] = f2bf(acc);
    return;
  }
  // b == 64: cfull = W3@(W2@b1+b2)+b3, then the 9 global consts
  float acc = b2[t];
  for (int c = 0; c < 512; ++c) acc += W2[t * 512 + c] * b1[c];
  t1[t] = acc;
  __syncthreads();
  if (t < 128) {
    float a = b3[t];
    for (int k = 0; k < 256; ++k) a += W3[t * 256 + k] * t1[k];
    cfull[t] = a;
    cf[t] = a;
  }
  __syncthreads();
  if (t < 64) {
    const int l = t;
    const float2 gv = ((const float2*)g)[l];
    const float2 bv = ((const float2*)lb)[l];
    const float2 fgv = ((const float2*)fg)[l];
    const float2 fbv = ((const float2*)fb)[l];
    const float2 wvv = ((const float2*)wv)[l];
    const float P0 = cf[2 * l] + bv.x, P1 = cf[2 * l + 1] + bv.y;
    const float w0 = fgv.x * wvv.x, w1 = fgv.y * wvv.y;
    float s[9];
    s[0] = P0 + P1;
    s[1] = P0 * w0 + P1 * w1;
    s[2] = P0 * P0 + P1 * P1;
    s[3] = gv.x + gv.y;
    s[4] = gv.x * w0 + gv.y * w1;
    s[5] = gv.x * gv.x + gv.y * gv.y;
    s[6] = P0 * gv.x + P1 * gv.y;
    s[7] = w0 + w1;
    s[8] = fbv.x * wvv.x + fbv.y * wvv.y;
#pragma unroll
    for (int m = 32; m >= 1; m >>= 1)
#pragma unroll
      for (int i = 0; i < 9; ++i) s[i] += __shfl_xor(s[i], m, 64);
    if (l == 0)
#pragma unroll
      for (int i = 0; i < 9; ++i) C[i] = s[i];
  }
}

// ============ fused node kernel: Q,K tables + fp32 23-scalar collapse =======
// Block 256 = 4 waves over a 64-node tile; wave w owns rows [16w,16w+16).
// Weights staged per pass into a 32KB XOR-swizzled LDS buffer (once per
// BLOCK, not per wave — kills the 4x redundant L2 weight traffic).
// MFMA 16x16x32 bf16: A-frag lane l -> X[m=l&15][k=32kb+8*(l>>4)+i];
// C/D: row=(l>>4)*4+r, col=l&15 (+16cb). Swizzle: byte ^ ((row&7)<<4).
__global__ __launch_bounds__(256) void k_node(
    const float* __restrict__ x, const unsigned short* __restrict__ Wqb,
    const unsigned short* __restrict__ Wkb,
    const unsigned short* __restrict__ Wvb,
    const unsigned short* __restrict__ A3b, const float* __restrict__ bq,
    const float* __restrict__ bk, const float* __restrict__ bv,
    const float* __restrict__ cfull, const float* __restrict__ g,
    const float* __restrict__ lb, const float* __restrict__ fg,
    const float* __restrict__ wvp, unsigned short* __restrict__ Qb,
    unsigned short* __restrict__ Kb, float* __restrict__ S, int N) {
  __shared__ unsigned short tile[64][136];
  __shared__ unsigned short wl[128 * 128];  // 32KB swizzled weight buffer
  const int t = threadIdx.x;
  const int nb = blockIdx.x * 64;
  // stage x -> bf16 tile (coalesced float4 loads); MFMA input only
  for (int i = t; i < 64 * 32; i += 256) {
    const int j = i >> 5, c4 = i & 31;
    const int n = nb + j;
    float4 v = make_float4(0.f, 0.f, 0.f, 0.f);
    if (n < N) v = ((const float4*)x)[(size_t)n * 32 + c4];
    unsigned int lo = f2bf(v.x) | ((unsigned int)f2bf(v.y) << 16);
    unsigned int hi = f2bf(v.z) | ((unsigned int)f2bf(v.w) << 16);
    *(uint2*)&tile[j][c4 << 2] = make_uint2(lo, hi);
  }
  __syncthreads();
  const int wv16 = __builtin_amdgcn_readfirstlane(t >> 6) * 16;
  const int l = t & 63;
  const int ln = l & 15, g4 = l >> 4;
  bf16x8 af[4];
#pragma unroll
  for (int kb = 0; kb < 4; ++kb)
    af[kb] = *(const bf16x8*)&tile[wv16 + ln][kb * 32 + g4 * 8];

// stage one 32KB matrix into wl, swizzled, whole block cooperating
#define STAGE_W(MAT)                                                          \
  {                                                                           \
    __syncthreads(); /* all waves done reading wl (previous pass) */          \
    _Pragma("unroll") for (int c = 0; c < 8; ++c) {                           \
      const int idx = c * 256 + t;                                            \
      const int byte = idx * 16;                                              \
      const int row = byte >> 8;                                              \
      const int swz = byte ^ ((row & 7) << 4);                                \
      *(uint4*)((char*)wl + swz) =                                            \
          *(const uint4*)((const char*)(MAT) + byte);                         \
    }                                                                         \
    __syncthreads();                                                          \
  }
// swizzled LDS read of a B-fragment (XOR applied to the INTEGER offset)
#define WFRAG(CB, KB)                                                         \
  (*(const bf16x8*)((const char*)wl +                                         \
                    (((((CB)*16 + ln) << 8) + (KB)*64 + g4 * 16) ^            \
                     ((ln & 7) << 4))))

  // ---- Q pass ----
  STAGE_W(Wqb)
#pragma unroll
  for (int cb = 0; cb < 8; ++cb) {
    f32x4 acc = {0.f, 0.f, 0.f, 0.f};
#pragma unroll
    for (int kb = 0; kb < 4; ++kb)
      acc = __builtin_amdgcn_mfma_f32_16x16x32_bf16(af[kb], WFRAG(cb, kb),
                                                    acc, 0, 0, 0);
    const int col = cb * 16 + ln;
    const float bs = bq[col];
#pragma unroll
    for (int r = 0; r < 4; ++r) tile[wv16 + g4 * 4 + r][col] = f2bf(acc[r] + bs);
  }
#pragma unroll
  for (int c = 0; c < 4; ++c) {
    const int row = wv16 + c * 4 + g4;
    const int n = nb + row;
    if (n < N)
      ((uint4*)(Qb + (size_t)n * 128))[ln] = *(const uint4*)&tile[row][ln * 8];
  }

  // ---- K pass ----
  STAGE_W(Wkb)
#pragma unroll
  for (int cb = 0; cb < 8; ++cb) {
    f32x4 acc = {0.f, 0.f, 0.f, 0.f};
#pragma unroll
    for (int kb = 0; kb < 4; ++kb)
      acc = __builtin_amdgcn_mfma_f32_16x16x32_bf16(af[kb], WFRAG(cb, kb),
                                                    acc, 0, 0, 0);
    const int col = cb * 16 + ln;
    const float bs = bk[col];
#pragma unroll
    for (int r = 0; r < 4; ++r) tile[wv16 + g4 * 4 + r][col] = f2bf(acc[r] + bs);
  }
#pragma unroll
  for (int c = 0; c < 4; ++c) {
    const int row = wv16 + c * 4 + g4;
    const int n = nb + row;
    if (n < N)
      ((uint4*)(Kb + (size_t)n * 128))[ln] = *(const uint4*)&tile[row][ln * 8];
  }

  // ---- V pass: uf fp32 regs (exact) + bf16 tile (VM MFMA input) ----
  STAGE_W(Wvb)
  float uf[8][4];
#pragma unroll
  for (int cb = 0; cb < 8; ++cb) {
    f32x4 acc = {0.f, 0.f, 0.f, 0.f};
#pragma unroll
    for (int kb = 0; kb < 4; ++kb)
      acc = __builtin_amdgcn_mfma_f32_16x16x32_bf16(af[kb], WFRAG(cb, kb),
                                                    acc, 0, 0, 0);
    const int col = cb * 16 + ln;
    const float bs = bv[col];
#pragma unroll
    for (int r = 0; r < 4; ++r) {
      const float v = fmaxf(acc[r] + bs, 0.f);
      uf[cb][r] = v;
      tile[wv16 + g4 * 4 + r][col] = f2bf(v);
    }
  }

  // ---- VM pass (own rows; stage barrier syncs all waves first) ----
  bf16x8 af2[4];
#pragma unroll
  for (int kb = 0; kb < 4; ++kb)
    af2[kb] = *(const bf16x8*)&tile[wv16 + ln][kb * 32 + g4 * 8];
  STAGE_W(A3b)
  float vmf[8][4];
#pragma unroll
  for (int cb = 0; cb < 8; ++cb) {
    f32x4 acc = {0.f, 0.f, 0.f, 0.f};
#pragma unroll
    for (int kb = 0; kb < 4; ++kb)
      acc = __builtin_amdgcn_mfma_f32_16x16x32_bf16(af2[kb], WFRAG(cb, kb),
                                                    acc, 0, 0, 0);
#pragma unroll
    for (int r = 0; r < 4; ++r) vmf[cb][r] = acc[r];
  }
#undef STAGE_W
#undef WFRAG

  // consts at this lane's 8 columns (L2-broadcast loads; no LDS)
  float gc[8], wc[8], Pc[8];
#pragma unroll
  for (int cb = 0; cb < 8; ++cb) {
    const int col = cb * 16 + ln;
    gc[cb] = g[col];
    wc[cb] = fg[col] * wvp[col];
    Pc[cb] = cfull[col] + lb[col];
  }

  // ---- 23-scalar collapse, all fp32 (round-5/7 numerics; x re-read fp32) ----
#pragma unroll
  for (int r = 0; r < 4; ++r) {
    const int row = wv16 + g4 * 4 + r;
    const int nrow = (nb + row < N) ? (nb + row) : (N - 1);  // clamp OOB
    float s[23];
#pragma unroll
    for (int i = 0; i < 23; ++i) s[i] = 0.f;
#pragma unroll
    for (int cb = 0; cb < 8; ++cb) {
      const float xv = x[(size_t)nrow * 128 + cb * 16 + ln];
      const float u = uf[cb][r];
      const float v = vmf[cb][r];
      const float gg = gc[cb], ww = wc[cb], PP = Pc[cb];
      const float xg = xv * gg, ug = u * gg;
      s[0] += xv;
      s[1] += u;
      s[2] += xv * xv;
      s[3] += xv * u;
      s[4] += u * u;
      s[5] += v;
      s[6] += v * ww;
      s[7] += xg;
      s[8] += ug;
      s[9] += xg * ww;
      s[10] += ug * ww;
      s[11] += PP * v;
      s[12] += v * v;
      s[13] += PP * xg;
      s[14] += PP * ug;
      s[15] += v * xg;
      s[16] += v * ug;
      s[17] += v * gg;
      s[18] += xg * xg;
      s[19] += xg * ug;
      s[20] += ug * ug;
      s[21] += xg * gg;
      s[22] += ug * gg;
    }
#pragma unroll
    for (int m = 1; m <= 8; m <<= 1)
#pragma unroll
      for (int i = 0; i < 23; ++i) s[i] += __shfl_xor(s[i], m, 64);
    const int n2 = nb + row;
    if (ln == 0 && n2 < N) {
      float* o = S + (size_t)n2 * 24;
      o[0] = s[0] * (1.f / 128.f);
      o[1] = s[1] * (1.f / 128.f);
#pragma unroll
      for (int i = 2; i < 23; ++i) o[i] = s[i];
      o[23] = 0.f;
    }
  }
}

// ============ edge pass 1: alpha + segment sum ============
__global__ __launch_bounds__(256) void k_edge_alpha(
    const int* __restrict__ ei, const unsigned short* __restrict__ Qb,
    const unsigned short* __restrict__ Kb, float* __restrict__ eArr,
    float* __restrict__ sArr, int E) {
  const int t = threadIdx.x;
  const int l = t & 15;
  const int e = blockIdx.x * 16 + (t >> 4);
  if (e >= E) return;
  const int src = ei[e];
  const int dst = ei[E + e];
  const uint4 qv = ((const uint4*)Qb)[(size_t)src * 16 + l];
  const uint4 kv = ((const uint4*)Kb)[(size_t)dst * 16 + l];
  float p = blo(qv.x) * blo(kv.x);
  p = fmaf(bhi(qv.x), bhi(kv.x), p);
  p = fmaf(blo(qv.y), blo(kv.y), p);
  p = fmaf(bhi(qv.y), bhi(kv.y), p);
  p = fmaf(blo(qv.z), blo(kv.z), p);
  p = fmaf(bhi(qv.z), bhi(kv.z), p);
  p = fmaf(blo(qv.w), blo(kv.w), p);
  p = fmaf(bhi(qv.w), bhi(kv.w), p);
#pragma unroll
  for (int m = 8; m >= 1; m >>= 1) p += __shfl_xor(p, m, 16);
  if (l == 0) {
    const float ex = __expf(p);  // max-shift dropped: exactly equivalent
    eArr[e] = ex;
    atomicAdd(&sArr[dst], ex);
  }
}

// ============ edge pass 2: closed-form logit ============
__global__ __launch_bounds__(256) void k_edge_out(
    const int* __restrict__ ei, const float* __restrict__ eArr,
    const float* __restrict__ sArr, const float* __restrict__ S,
    const float* __restrict__ C, const float* __restrict__ bvec,
    float* __restrict__ out, int E) {
  const int e = blockIdx.x * 256 + threadIdx.x;
  if (e >= E) return;
  const int dst = ei[E + e];
  const float t = eArr[e] / (sArr[dst] + 1e-16f);
  const float4* o = (const float4*)(S + (size_t)dst * 24);
  const float4 q0 = o[0], q1 = o[1], q2 = o[2], q3 = o[3], q4 = o[4],
               q5 = o[5];
  const float mx = q0.x, mU = q0.y, sxx = q0.z, sxu = q0.w;
  const float suu = q1.x, sv = q1.y, svw = q1.z, sxg = q1.w;
  const float sug = q2.x, sxgw = q2.y, sugw = q2.z, spv = q2.w;
  const float svv = q3.x, pxg = q3.y, pug = q3.z, vxg = q3.w;
  const float vug = q4.x, vg = q4.y, xgxg = q4.z, xgug = q4.w;
  const float ugug = q5.x, xgg = q5.y, ugg = q5.z;
  const float SP = C[0], SPw = C[1], SPP = C[2], SG = C[3], SGw = C[4],
              GG = C[5], SPG = C[6], Sw = C[7], s0 = C[8];
  const float mu = mx + t * mU;
  const float qy = (sxx + 2.f * t * sxu + t * t * suu) * (1.f / 128.f);
  const float i1 = rsqrtf(qy - mu * mu + 1e-5f);
  const float sz = SP + t * sv + i1 * (sxg + t * sug - mu * SG);
  const float szw = SPw + t * svw + i1 * (sxgw + t * sugw - mu * SGw);
  const float cross = pxg + t * (pug + vxg) + t * t * vug - mu * (SPG + t * vg);
  const float rr = xgxg + 2.f * t * xgug + t * t * ugug -
                   2.f * mu * (xgg + t * ugg) + mu * mu * GG;
  const float szz =
      SPP + 2.f * t * spv + t * t * svv + 2.f * i1 * cross + i1 * i1 * rr;
  const float muz = sz * (1.f / 128.f);
  const float varz = szz * (1.f / 128.f) - muz * muz;
  const float iz = rsqrtf(varz + 1e-5f);
  out[e] = iz * (szw - muz * Sw) + s0 + bvec[0];
}

extern "C" void kernel_launch(void* const* d_in, const int* in_sizes, int n_in,
                              void* d_out, int out_size, void* d_ws,
                              size_t ws_size, hipStream_t stream) {
  const int* ei = (const int*)d_in[0];
  const float* x = (const float*)d_in[1];
  const float* Wq = (const float*)d_in[2];
  const float* bq = (const float*)d_in[3];
  const float* Wk = (const float*)d_in[4];
  const float* bk = (const float*)d_in[5];
  const float* Wv = (const float*)d_in[6];
  const float* bv = (const float*)d_in[7];
  const float* ln_g = (const float*)d_in[8];
  const float* ln_b = (const float*)d_in[9];
  const float* W1 = (const float*)d_in[10];
  const float* b1 = (const float*)d_in[11];
  const float* W2 = (const float*)d_in[12];
  const float* b2 = (const float*)d_in[13];
  const float* W3 = (const float*)d_in[14];
  const float* b3 = (const float*)d_in[15];
  const float* Wvec = (const float*)d_in[16];
  const float* bvec = (const float*)d_in[17];
  const float* fn_g = (const float*)d_in[18];
  const float* fn_b = (const float*)d_in[19];

  const int E = in_sizes[0] / 2;
  const int N = in_sizes[1] / 128;

  // only layer 2 is live
  const float* Wq2 = Wq + 2 * 128 * 128;
  const float* bq2 = bq + 2 * 128;
  const float* Wk2 = Wk + 2 * 128 * 128;
  const float* bk2 = bk + 2 * 128;
  const float* Wv2 = Wv + 2 * 128 * 128;
  const float* bv2 = bv + 2 * 128;
  const float* g2 = ln_g + 2 * 128;
  const float* lb2 = ln_b + 2 * 128;

  float* ws = (float*)d_ws;
  float* T = ws;                 // 32768
  float* cfull = T + 32768;      // 128
  float* consts = cfull + 128;   // 16
  unsigned short* Wqb = (unsigned short*)(consts + 16);  // 16384 us each
  unsigned short* Wkb = Wqb + 16384;
  unsigned short* Wvb = Wkb + 16384;
  unsigned short* A3b = Wvb + 16384;
  float* fbase = consts + 16 + 32768;  // after 4*16384 bf16 = 32768 floats
  unsigned short* Qb = (unsigned short*)fbase;  // N*128 bf16
  unsigned short* Kb = Qb + (size_t)N * 128;
  float* S = fbase + (size_t)N * 128;  // N*24 (after Qb+Kb)
  float* eArr = S + (size_t)N * 24;    // E
  float* sArr = eArr + E;              // N

  const int zblk = (N + 127) / 128;
  k_TW<<<640 + zblk, 128, 0, stream>>>(W2, W1, Wq2, Wk2, Wv2, T, Wqb, Wkb,
                                       Wvb, sArr, N);
  k_Ac<<<65, 256, 0, stream>>>(W3, T, W2, b1, b2, b3, g2, lb2, fn_g, fn_b,
                               Wvec, A3b, cfull, consts);

  const int nblk = (N + 63) / 64;
  k_node<<<nblk, 256, 0, stream>>>(x, Wqb, Wkb, Wvb, A3b, bq2, bk2, bv2,
                                   cfull, g2, lb2, fn_g, Wvec, Qb, Kb, S, N);
  const int ablk = (E + 15) / 16;
  k_edge_alpha<<<ablk, 256, 0, stream>>>(ei, Qb, Kb, eArr, sArr, E);
  const int oblk = (E + 255) / 256;
  k_edge_out<<<oblk, 256, 0, stream>>>(ei, eArr, sArr, S, consts, bvec,
                                       (float*)d_out, E);
}